// Round 8
// baseline (175.966 us; speedup 1.0000x reference)
//
#include <hip/hip_runtime.h>

#define I_TOTAL 100000
#define DIM 64
#define BS 256

typedef __attribute__((ext_vector_type(8))) short bf16x8;
typedef __attribute__((ext_vector_type(4))) float f32x4;

__device__ inline unsigned short f2bf(float x) {
    union { float f; unsigned u; } v; v.f = x;
    return (unsigned short)((v.u + 0x8000u) >> 16);   // round-half-up to bf16
}

// Packed fp32->bf16 (RNE). No builtin on gfx950 -> inline asm.
__device__ inline unsigned pk_bf16(float lo, float hi) {
    unsigned r;
    asm("v_cvt_pk_bf16_f32 %0, %1, %2" : "=v"(r) : "v"(lo), "v"(hi));
    return r;
}

__device__ inline bf16x8 pack8(float4 a, float4 b) {
    union { unsigned u[4]; bf16x8 v; } r;
    r.u[0] = pk_bf16(a.x, a.y);
    r.u[1] = pk_bf16(a.z, a.w);
    r.u[2] = pk_bf16(b.x, b.y);
    r.u[3] = pk_bf16(b.z, b.w);
    return r.v;
}

// uniform-value float -> SGPR
__device__ inline float rfl(float x) {
    union { float f; int i; } u; u.f = x;
    u.i = __builtin_amdgcn_readfirstlane(u.i);
    return u.f;
}

// Convert item table fp32 -> bf16 once (BW-bound, ~6.5 us).
__global__ __launch_bounds__(256) void conv_items(
    const float* __restrict__ item, unsigned short* __restrict__ itbf)
{
    long t = (long)blockIdx.x * 256 + threadIdx.x;   // 0..799999
    const float4* p = (const float4*)(item + t * 8);
    float4 a = p[0], b = p[1];
    ushort4 r0, r1;
    r0.x = f2bf(a.x); r0.y = f2bf(a.y); r0.z = f2bf(a.z); r0.w = f2bf(a.w);
    r1.x = f2bf(b.x); r1.y = f2bf(b.y); r1.z = f2bf(b.z); r1.w = f2bf(b.w);
    ushort4* q = (ushort4*)(itbf + t * 8);
    q[0] = r0; q[1] = r1;
}

// 10 MFMAs of one 16i x 16b tile (K=64), swapped operands (items = A-operand):
// D[m=i (quad*4+reg)][n=b (lane&15)] -> each lane's f32x4 = 4 consecutive i
// for one b -> direct stores, no LDS.
__device__ inline void mfma_tile_sw(const bf16x8 (&afr)[5][2], bf16x8 b0, bf16x8 b1,
                                    f32x4 (&acc)[5])
{
    const f32x4 zero = (f32x4){0.f, 0.f, 0.f, 0.f};
#pragma unroll
    for (int c = 0; c < 5; ++c) {
        acc[c] = __builtin_amdgcn_mfma_f32_16x16x32_bf16(b0, afr[c][0], zero, 0, 0, 0);
        acc[c] = __builtin_amdgcn_mfma_f32_16x16x32_bf16(b1, afr[c][1], acc[c], 0, 0, 0);
    }
}

// softmax-EV of one tile's acc -> f32x4 (4 consecutive i for this lane's b).
__device__ inline f32x4 softmax_vec(const f32x4 (&acc)[5], const float (&sw)[5],
                                    const float (&swv)[5])
{
    f32x4 r;
#pragma unroll
    for (int rr = 0; rr < 4; ++rr) {
        float e0 = __builtin_amdgcn_exp2f(acc[0][rr]);
        float e1 = __builtin_amdgcn_exp2f(acc[1][rr]);
        float e2 = __builtin_amdgcn_exp2f(acc[2][rr]);
        float e3 = __builtin_amdgcn_exp2f(acc[3][rr]);
        float e4 = __builtin_amdgcn_exp2f(acc[4][rr]);
        float den = e0 * sw[0];
        den = fmaf(e1, sw[1], den);
        den = fmaf(e2, sw[2], den);
        den = fmaf(e3, sw[3], den);
        den = fmaf(e4, sw[4], den);
        float num = e0 * swv[0];
        num = fmaf(e1, swv[1], num);
        num = fmaf(e2, swv[2], num);
        num = fmaf(e3, swv[3], num);
        num = fmaf(e4, swv[4], num);
        r[rr] = num * __builtin_amdgcn_rcpf(den);
    }
    return r;
}

// ---- 4-tile group helpers (g is a compile-time literal at every call) ----
__device__ inline void load_group(const unsigned short* bp, int g,
                                  bf16x8 (&v0)[4], bf16x8 (&v1)[4])
{
#pragma unroll
    for (int t = 0; t < 4; ++t) {
        const unsigned short* p = bp + (size_t)(g * 4 + t) * 1024;
        v0[t] = *(const bf16x8*)p;
        v1[t] = *(const bf16x8*)(p + 32);
    }
}

__device__ inline void comp_group(const bf16x8 (&afr)[5][2],
                                  const bf16x8 (&v0)[4], const bf16x8 (&v1)[4],
                                  const float (&sw)[5], const float (&swv)[5],
                                  f32x4 (&r)[4])
{
#pragma unroll
    for (int t = 0; t < 4; ++t) {
        f32x4 acc[5];
        mfma_tile_sw(afr, v0[t], v1[t], acc);
        r[t] = softmax_vec(acc, sw, swv);
    }
}

__device__ inline void store_group(float* op, int g, const f32x4 (&r)[4])
{
#pragma unroll
    for (int t = 0; t < 4; ++t)
        __builtin_nontemporal_store(r[t], (f32x4*)(op + (g * 4 + t) * 16));
}

// Main kernel, 1-wave workgroups, zero LDS, vmcnt-safe schedule.
// KEY CHANGE (theory: single in-order vmcnt counter covers loads AND stores
// on gfx9-lineage, so any load issued after a store cannot be waited on
// without draining the store to L2/HBM; every previous variant interleaved
// store(t) before load(t+1) -> one store-commit round trip per tile group
// that TLP never hid -> ~55 us floor). Schedule below issues every group's
// loads BEFORE any younger store, so all compute waits are pure-load
// vmcnt(N) and stores retire in the background:
//   LA(g0) LB(g1) C(A) LA(g2) S(g0) C(B) LB(g3) S(g1) C(A) S(g2) C(B) S(g3)
// 6656 blocks = 104 y x 16 g x 4 i-sub (384 no-op); blk&7 keys y-set to XCD.
// Wave: 16 b x 256 i (16 tiles), 5 classes.
__global__ __launch_bounds__(64) void gemm_softmax(
    const unsigned short* __restrict__ itbf,
    const int* __restrict__ bu, const float* __restrict__ ut,
    const float* __restrict__ cw, const float* __restrict__ clsb,
    const float* __restrict__ vals, float* __restrict__ out)
{
    const int blk  = blockIdx.x;
    const int r8   = blk & 7;
    const int rest = blk >> 3;       // 0..831
    const int wv   = rest & 3;       // i-subrange within y
    const int qq   = rest >> 2;      // 0..207
    const int g    = qq & 15;        // b-group (16 b each)
    const int a    = qq >> 4;        // 0..12
    const int y    = a * 8 + r8;     // i-range id, 0..103
    if (y >= 98) return;

    const int lane = threadIdx.x & 63;
    const int col  = lane & 15;     // b within group (D col) / item row in tile
    const int quad = lane >> 4;

    const int b_base = g * 16;
    const int i_base = y * 1024 + wv * 256;   // this wave's 16 i-tiles
    if (i_base >= I_TOTAL) return;            // y==97, wv==3

    const float s = 1.4426950408889634f;      // log2(e)

    // ---- A-prep in-register: M = u * W * log2e (bf16 fragments) ----
    const float* up = ut + (size_t)bu[b_base + col] * DIM + quad * 8;
    float4 u0 = *(const float4*)(up);
    float4 u1 = *(const float4*)(up + 4);
    float4 u2 = *(const float4*)(up + 32);
    float4 u3 = *(const float4*)(up + 36);
    u0.x *= s; u0.y *= s; u0.z *= s; u0.w *= s;
    u1.x *= s; u1.y *= s; u1.z *= s; u1.w *= s;
    u2.x *= s; u2.y *= s; u2.z *= s; u2.w *= s;
    u3.x *= s; u3.y *= s; u3.z *= s; u3.w *= s;

    bf16x8 afr[5][2];
    float sw[5], swv[5];
#pragma unroll
    for (int c = 0; c < 5; ++c) {
        const float* wp = cw + c * DIM + quad * 8;
        float4 w0 = *(const float4*)(wp);
        float4 w1 = *(const float4*)(wp + 4);
        float4 w2 = *(const float4*)(wp + 32);
        float4 w3 = *(const float4*)(wp + 36);
        float4 m0 = make_float4(u0.x*w0.x, u0.y*w0.y, u0.z*w0.z, u0.w*w0.w);
        float4 m1 = make_float4(u1.x*w1.x, u1.y*w1.y, u1.z*w1.z, u1.w*w1.w);
        float4 m2 = make_float4(u2.x*w2.x, u2.y*w2.y, u2.z*w2.z, u2.w*w2.w);
        float4 m3 = make_float4(u3.x*w3.x, u3.y*w3.y, u3.z*w3.z, u3.w*w3.w);
        afr[c][0] = pack8(m0, m1);
        afr[c][1] = pack8(m2, m3);
        float w = __builtin_amdgcn_exp2f(clsb[c] * s);   // exp2(bias*log2e)
        sw[c]  = rfl(w);
        swv[c] = rfl(w * vals[c]);
    }

    const unsigned short* bp = itbf + (size_t)(i_base + col) * DIM + quad * 8;
    float* op = out + (size_t)(b_base + col) * I_TOTAL + i_base + quad * 4;

    if (i_base + 256 <= I_TOTAL) {
        // ---- fast path: ping-pong 4-tile groups, loads always older than
        //      younger stores -> no store drain on any compute wait ----
        bf16x8 pa0[4], pa1[4], pb0[4], pb1[4];
        f32x4  r[4];

        load_group(bp, 0, pa0, pa1);           // queue: A0(8)
        load_group(bp, 1, pb0, pb1);           // queue: A0 B1
        comp_group(afr, pa0, pa1, sw, swv, r); // wait A0 -> vmcnt(8)
        load_group(bp, 2, pa0, pa1);           // queue: B1 A2   (before S0!)
        store_group(op, 0, r);                 // queue: B1 A2 S0
        comp_group(afr, pb0, pb1, sw, swv, r); // wait B1 -> vmcnt(12), no drain
        load_group(bp, 3, pb0, pb1);           // queue: A2 S0 B3
        store_group(op, 1, r);                 // queue: A2 S0 B3 S1
        comp_group(afr, pa0, pa1, sw, swv, r); // wait A2 -> vmcnt(16)
        store_group(op, 2, r);
        comp_group(afr, pb0, pb1, sw, swv, r); // wait B3 -> vmcnt(8)
        store_group(op, 3, r);
    } else {
        // ---- tail path (y==97, wv==2): clamp loads, guard stores ----
#pragma unroll 1
        for (int t = 0; t < 16; ++t) {
            if (i_base + t * 16 >= I_TOTAL) break;
            int irow = i_base + t * 16 + col;             // item row this lane loads
            int ic = irow < I_TOTAL ? irow : I_TOTAL - 1;
            const unsigned short* p2 = itbf + (size_t)ic * DIM + quad * 8;
            bf16x8 b0 = *(const bf16x8*)p2;
            bf16x8 b1 = *(const bf16x8*)(p2 + 32);
            f32x4 acc[5];
            mfma_tile_sw(afr, b0, b1, acc);
            f32x4 r = softmax_vec(acc, sw, swv);
            int ie = i_base + t * 16 + quad * 4;          // first i this lane stores
#pragma unroll
            for (int rr = 0; rr < 4; ++rr) {
                if (ie + rr < I_TOTAL)
                    out[(size_t)(b_base + col) * I_TOTAL + ie + rr] = r[rr];
            }
        }
    }
}

// Fallback (no workspace): same structure, fp32 item loads + inline convert.
__global__ __launch_bounds__(64) void gemm_softmax_fb(
    const int* __restrict__ bu, const float* __restrict__ ut,
    const float* __restrict__ it, const float* __restrict__ cw,
    const float* __restrict__ clsb, const float* __restrict__ vals,
    float* __restrict__ out)
{
    const int blk  = blockIdx.x;
    const int r8   = blk & 7;
    const int rest = blk >> 3;
    const int wv   = rest & 3;
    const int qq   = rest >> 2;
    const int g    = qq & 15;
    const int a    = qq >> 4;
    const int y    = a * 8 + r8;
    if (y >= 98) return;

    const int lane = threadIdx.x & 63;
    const int col  = lane & 15;
    const int quad = lane >> 4;

    const int b_base = g * 16;
    const int i_base = y * 1024 + wv * 256;
    if (i_base >= I_TOTAL) return;

    const float s = 1.4426950408889634f;

    const float* up = ut + (size_t)bu[b_base + col] * DIM + quad * 8;
    float4 u0 = *(const float4*)(up);
    float4 u1 = *(const float4*)(up + 4);
    float4 u2 = *(const float4*)(up + 32);
    float4 u3 = *(const float4*)(up + 36);
    u0.x *= s; u0.y *= s; u0.z *= s; u0.w *= s;
    u1.x *= s; u1.y *= s; u1.z *= s; u1.w *= s;
    u2.x *= s; u2.y *= s; u2.z *= s; u2.w *= s;
    u3.x *= s; u3.y *= s; u3.z *= s; u3.w *= s;

    bf16x8 afr[5][2];
    float sw[5], swv[5];
#pragma unroll
    for (int c = 0; c < 5; ++c) {
        const float* wp = cw + c * DIM + quad * 8;
        float4 w0 = *(const float4*)(wp);
        float4 w1 = *(const float4*)(wp + 4);
        float4 w2 = *(const float4*)(wp + 32);
        float4 w3 = *(const float4*)(wp + 36);
        float4 m0 = make_float4(u0.x*w0.x, u0.y*w0.y, u0.z*w0.z, u0.w*w0.w);
        float4 m1 = make_float4(u1.x*w1.x, u1.y*w1.y, u1.z*w1.z, u1.w*w1.w);
        float4 m2 = make_float4(u2.x*w2.x, u2.y*w2.y, u2.z*w2.z, u2.w*w2.w);
        float4 m3 = make_float4(u3.x*w3.x, u3.y*w3.y, u3.z*w3.z, u3.w*w3.w);
        afr[c][0] = pack8(m0, m1);
        afr[c][1] = pack8(m2, m3);
        float w = __builtin_amdgcn_exp2f(clsb[c] * s);
        sw[c]  = rfl(w);
        swv[c] = rfl(w * vals[c]);
    }

#pragma unroll 1
    for (int t = 0; t < 16; ++t) {
        if (i_base + t * 16 >= I_TOTAL) break;
        int irow = i_base + t * 16 + col;
        int ic = irow < I_TOTAL ? irow : I_TOTAL - 1;
        const float* p2 = it + (size_t)ic * DIM + quad * 8;
        float4 q0 = *(const float4*)(p2);
        float4 q1 = *(const float4*)(p2 + 4);
        float4 q2 = *(const float4*)(p2 + 32);
        float4 q3 = *(const float4*)(p2 + 36);
        bf16x8 b0 = pack8(q0, q1);
        bf16x8 b1 = pack8(q2, q3);
        f32x4 acc[5];
        mfma_tile_sw(afr, b0, b1, acc);
        f32x4 r = softmax_vec(acc, sw, swv);
        int ie = i_base + t * 16 + quad * 4;
        if (ie + 4 <= I_TOTAL) {
            __builtin_nontemporal_store(r,
                (f32x4*)(out + (size_t)(b_base + col) * I_TOTAL + ie));
        } else {
#pragma unroll
            for (int rr = 0; rr < 4; ++rr)
                if (ie + rr < I_TOTAL)
                    out[(size_t)(b_base + col) * I_TOTAL + ie + rr] = r[rr];
        }
    }
}

extern "C" void kernel_launch(void* const* d_in, const int* in_sizes, int n_in,
                              void* d_out, int out_size, void* d_ws, size_t ws_size,
                              hipStream_t stream) {
    const int*   bu   = (const int*)d_in[0];
    const float* ut   = (const float*)d_in[1];
    const float* it   = (const float*)d_in[2];
    const float* cw   = (const float*)d_in[3];
    const float* cb   = (const float*)d_in[4];
    const float* vals = (const float*)d_in[5];
    float* out = (float*)d_out;
    unsigned short* itbf = (unsigned short*)d_ws;    // 12.8 MB

    const size_t needed = (size_t)I_TOTAL * DIM * 2;

    if (ws_size >= needed) {
        conv_items<<<3125, 256, 0, stream>>>(it, itbf);
        gemm_softmax<<<6656, 64, 0, stream>>>(itbf, bu, ut, cw, cb, vals, out);
    } else {
        gemm_softmax_fb<<<6656, 64, 0, stream>>>(bu, ut, it, cw, cb, vals, out);
    }
}

// Round 11
// 172.074 us; speedup vs baseline: 1.0226x; 1.0226x over previous
//
#include <hip/hip_runtime.h>

#define I_TOTAL 100000
#define DIM 64
#define BS 256

typedef __attribute__((ext_vector_type(8))) short bf16x8;
typedef __attribute__((ext_vector_type(4))) float f32x4;

__device__ inline unsigned short f2bf(float x) {
    union { float f; unsigned u; } v; v.f = x;
    return (unsigned short)((v.u + 0x8000u) >> 16);   // round-half-up to bf16
}

// Packed fp32->bf16 (RNE). No builtin on gfx950 -> inline asm.
__device__ inline unsigned pk_bf16(float lo, float hi) {
    unsigned r;
    asm("v_cvt_pk_bf16_f32 %0, %1, %2" : "=v"(r) : "v"(lo), "v"(hi));
    return r;
}

__device__ inline bf16x8 pack8(float4 a, float4 b) {
    union { unsigned u[4]; bf16x8 v; } r;
    r.u[0] = pk_bf16(a.x, a.y);
    r.u[1] = pk_bf16(a.z, a.w);
    r.u[2] = pk_bf16(b.x, b.y);
    r.u[3] = pk_bf16(b.z, b.w);
    return r.v;
}

// uniform-value float -> SGPR
__device__ inline float rfl(float x) {
    union { float f; int i; } u; u.f = x;
    u.i = __builtin_amdgcn_readfirstlane(u.i);
    return u.f;
}

// Convert item table fp32 -> bf16 once (BW-bound, ~6.5 us).
__global__ __launch_bounds__(256) void conv_items(
    const float* __restrict__ item, unsigned short* __restrict__ itbf)
{
    long t = (long)blockIdx.x * 256 + threadIdx.x;   // 0..799999
    const float4* p = (const float4*)(item + t * 8);
    float4 a = p[0], b = p[1];
    ushort4 r0, r1;
    r0.x = f2bf(a.x); r0.y = f2bf(a.y); r0.z = f2bf(a.z); r0.w = f2bf(a.w);
    r1.x = f2bf(b.x); r1.y = f2bf(b.y); r1.z = f2bf(b.z); r1.w = f2bf(b.w);
    ushort4* q = (ushort4*)(itbf + t * 8);
    q[0] = r0; q[1] = r1;
}

// 10 MFMAs of one 16i x 16b tile (K=64), swapped operands (items = A-operand):
// D[m=i (quad*4+reg)][n=b (lane&15)] -> each lane's f32x4 = 4 consecutive i
// for one b -> direct stores, no transpose. (Numerics proven in R7.)
__device__ inline void mfma_tile_sw(const bf16x8 (&afr)[5][2], bf16x8 b0, bf16x8 b1,
                                    f32x4 (&acc)[5])
{
    const f32x4 zero = (f32x4){0.f, 0.f, 0.f, 0.f};
#pragma unroll
    for (int c = 0; c < 5; ++c) {
        acc[c] = __builtin_amdgcn_mfma_f32_16x16x32_bf16(b0, afr[c][0], zero, 0, 0, 0);
        acc[c] = __builtin_amdgcn_mfma_f32_16x16x32_bf16(b1, afr[c][1], acc[c], 0, 0, 0);
    }
}

// softmax-EV of one tile's acc -> f32x4 (4 consecutive i for this lane's b).
__device__ inline f32x4 softmax_vec(const f32x4 (&acc)[5], const float (&sw)[5],
                                    const float (&swv)[5])
{
    f32x4 r;
#pragma unroll
    for (int rr = 0; rr < 4; ++rr) {
        float e0 = __builtin_amdgcn_exp2f(acc[0][rr]);
        float e1 = __builtin_amdgcn_exp2f(acc[1][rr]);
        float e2 = __builtin_amdgcn_exp2f(acc[2][rr]);
        float e3 = __builtin_amdgcn_exp2f(acc[3][rr]);
        float e4 = __builtin_amdgcn_exp2f(acc[4][rr]);
        float den = e0 * sw[0];
        den = fmaf(e1, sw[1], den);
        den = fmaf(e2, sw[2], den);
        den = fmaf(e3, sw[3], den);
        den = fmaf(e4, sw[4], den);
        float num = e0 * swv[0];
        num = fmaf(e1, swv[1], num);
        num = fmaf(e2, swv[2], num);
        num = fmaf(e3, swv[3], num);
        num = fmaf(e4, swv[4], num);
        r[rr] = num * __builtin_amdgcn_rcpf(den);
    }
    return r;
}

// Main kernel, 1-wave workgroups, enforced asm pipeline — REGISTER staged.
// R9/R10's LDS-ring variant failed numerics twice (unlocalized in the
// global_load_lds/ds_read machinery); this keeps the counted-vmcnt schedule
// but stages tiles into a depth-3 register ring via asm global_load_dwordx4:
//  - asm loads with explicit "=&v" dests (per-lane, same pattern R7 proved),
//  - hand-counted s_waitcnt vmcnt(N) + sched_barrier(0) (rule #18),
//  - asm global_store_dwordx4 so the vm issue-order is exactly the asm order,
//  - per round, loads of tile T+3 are issued BEFORE the store of tile T ->
//    every compute wait is a pure-load wait; stores retire in background.
// NWAIT(T) = #vm-ops issued after L(T): R0:4 R1:5 R2:6 R3-13:7 R14:5 R15:3.
// (Compiler-inserted loads/waits interleave only in the safe direction:
//  they are younger than the waited-on loads, and the compiler's own waits
//  can only over-drain.)
// Wave: 16 b x 256 i (16 tiles), 5 classes. 6656 blocks; blk&7 -> XCD key.
__global__ __launch_bounds__(64) void gemm_softmax(
    const unsigned short* __restrict__ itbf,
    const int* __restrict__ bu, const float* __restrict__ ut,
    const float* __restrict__ cw, const float* __restrict__ clsb,
    const float* __restrict__ vals, float* __restrict__ out)
{
    const int blk  = blockIdx.x;
    const int r8   = blk & 7;
    const int rest = blk >> 3;       // 0..831
    const int wv   = rest & 3;       // i-subrange within y
    const int qq   = rest >> 2;      // 0..207
    const int g    = qq & 15;        // b-group (16 b each)
    const int a    = qq >> 4;        // 0..12
    const int y    = a * 8 + r8;     // i-range id, 0..103
    if (y >= 98) return;

    const int lane = threadIdx.x & 63;
    const int col  = lane & 15;      // b within group (D col) / item row in tile
    const int quad = lane >> 4;

    const int b_base = g * 16;
    const int i_base = y * 1024 + wv * 256;   // this wave's 16 i-tiles
    if (i_base >= I_TOTAL) return;            // y==97, wv==3

    const float s = 1.4426950408889634f;      // log2(e)

    const unsigned short* bp = itbf + (size_t)(i_base + col) * DIM + quad * 8;
    const bool fast = (i_base + 256 <= I_TOTAL);

// issue tile T's two 16B loads into registers R0w,R1w (asm, ordered)
#define LOADT(T, R0w, R1w) do {                                               \
    unsigned long long la0 = (unsigned long long)(bp + (size_t)(T) * 1024);   \
    unsigned long long la1 = la0 + 64;                                        \
    asm volatile("global_load_dwordx4 %0, %1, off"                            \
                 : "=&v"(R0w) : "v"(la0) : "memory");                         \
    asm volatile("global_load_dwordx4 %0, %1, off"                            \
                 : "=&v"(R1w) : "v"(la1) : "memory");                         \
} while (0)

#define WAITN(NW) do {                                                        \
    asm volatile("s_waitcnt vmcnt(" #NW ")" ::: "memory");                    \
    __builtin_amdgcn_sched_barrier(0);                                        \
} while (0)

    bf16x8 sA0, sA1, sB0, sB1, sC0, sC1;
    if (fast) {                       // prologue: 6 load ops, no stores yet
        LOADT(0, sA0, sA1);
        LOADT(1, sB0, sB1);
        LOADT(2, sC0, sC1);
    }

    // ---- A-prep in-register: M = u * W * log2e (bf16 fragments) ----
    // (source-after the prologue asm; its loads are younger than L(0..2),
    //  which only strengthens the NWAIT guarantees)
    const float* up = ut + (size_t)bu[b_base + col] * DIM + quad * 8;
    float4 u0 = *(const float4*)(up);
    float4 u1 = *(const float4*)(up + 4);
    float4 u2 = *(const float4*)(up + 32);
    float4 u3 = *(const float4*)(up + 36);
    u0.x *= s; u0.y *= s; u0.z *= s; u0.w *= s;
    u1.x *= s; u1.y *= s; u1.z *= s; u1.w *= s;
    u2.x *= s; u2.y *= s; u2.z *= s; u2.w *= s;
    u3.x *= s; u3.y *= s; u3.z *= s; u3.w *= s;

    bf16x8 afr[5][2];
    float sw[5], swv[5];
#pragma unroll
    for (int c = 0; c < 5; ++c) {
        const float* wp = cw + c * DIM + quad * 8;
        float4 w0 = *(const float4*)(wp);
        float4 w1 = *(const float4*)(wp + 4);
        float4 w2 = *(const float4*)(wp + 32);
        float4 w3 = *(const float4*)(wp + 36);
        float4 m0 = make_float4(u0.x*w0.x, u0.y*w0.y, u0.z*w0.z, u0.w*w0.w);
        float4 m1 = make_float4(u1.x*w1.x, u1.y*w1.y, u1.z*w1.z, u1.w*w1.w);
        float4 m2 = make_float4(u2.x*w2.x, u2.y*w2.y, u2.z*w2.z, u2.w*w2.w);
        float4 m3 = make_float4(u3.x*w3.x, u3.y*w3.y, u3.z*w3.z, u3.w*w3.w);
        afr[c][0] = pack8(m0, m1);
        afr[c][1] = pack8(m2, m3);
        float w = __builtin_amdgcn_exp2f(clsb[c] * s);   // exp2(bias*log2e)
        sw[c]  = rfl(w);
        swv[c] = rfl(w * vals[c]);
    }

    float* op = out + (size_t)(b_base + col) * I_TOTAL + i_base + quad * 4;

    if (fast) {
#define STORET(T, R) do {                                                     \
    unsigned long long ad = (unsigned long long)(op + (T) * 16);              \
    asm volatile("global_store_dwordx4 %0, %1, off"                           \
                 :: "v"(ad), "v"(R) : "memory");                              \
} while (0)

// consume slot (S0,S1) for tile T, refill same slot with tile T+3, store T.
// Source order: MFMA reads OLD S0/S1 before LOADT reassigns them (SSA).
#define ROUND_L(T, NW, S0, S1) do {                                           \
    WAITN(NW);                                                                \
    f32x4 acc[5];                                                             \
    mfma_tile_sw(afr, S0, S1, acc);                                           \
    LOADT((T) + 3, S0, S1);                                                   \
    f32x4 r = softmax_vec(acc, sw, swv);                                      \
    STORET(T, r);                                                             \
} while (0)

#define ROUND_N(T, NW, S0, S1) do {                                           \
    WAITN(NW);                                                                \
    f32x4 acc[5];                                                             \
    mfma_tile_sw(afr, S0, S1, acc);                                           \
    f32x4 r = softmax_vec(acc, sw, swv);                                      \
    STORET(T, r);                                                             \
} while (0)

        ROUND_L(0,  4, sA0, sA1);
        ROUND_L(1,  5, sB0, sB1);
        ROUND_L(2,  6, sC0, sC1);
        ROUND_L(3,  7, sA0, sA1);
        ROUND_L(4,  7, sB0, sB1);
        ROUND_L(5,  7, sC0, sC1);
        ROUND_L(6,  7, sA0, sA1);
        ROUND_L(7,  7, sB0, sB1);
        ROUND_L(8,  7, sC0, sC1);
        ROUND_L(9,  7, sA0, sA1);
        ROUND_L(10, 7, sB0, sB1);
        ROUND_L(11, 7, sC0, sC1);
        ROUND_L(12, 7, sA0, sA1);
        ROUND_N(13, 7, sB0, sB1);
        ROUND_N(14, 5, sC0, sC1);
        ROUND_N(15, 3, sA0, sA1);
#undef ROUND_L
#undef ROUND_N
#undef STORET
    } else {
        // ---- tail path (y==97, wv==2): clamp loads, guard stores ----
#pragma unroll 1
        for (int t = 0; t < 16; ++t) {
            if (i_base + t * 16 >= I_TOTAL) break;
            int irow = i_base + t * 16 + col;
            int ic = irow < I_TOTAL ? irow : I_TOTAL - 1;
            const unsigned short* p2 = itbf + (size_t)ic * DIM + quad * 8;
            bf16x8 b0 = *(const bf16x8*)p2;
            bf16x8 b1 = *(const bf16x8*)(p2 + 32);
            f32x4 acc[5];
            mfma_tile_sw(afr, b0, b1, acc);
            f32x4 r = softmax_vec(acc, sw, swv);
            int ie = i_base + t * 16 + quad * 4;
#pragma unroll
            for (int rr = 0; rr < 4; ++rr) {
                if (ie + rr < I_TOTAL)
                    out[(size_t)(b_base + col) * I_TOTAL + ie + rr] = r[rr];
            }
        }
    }
#undef LOADT
#undef WAITN
}

// Fallback (no workspace): fp32 item loads + inline convert, register path.
__global__ __launch_bounds__(64) void gemm_softmax_fb(
    const int* __restrict__ bu, const float* __restrict__ ut,
    const float* __restrict__ it, const float* __restrict__ cw,
    const float* __restrict__ clsb, const float* __restrict__ vals,
    float* __restrict__ out)
{
    const int blk  = blockIdx.x;
    const int r8   = blk & 7;
    const int rest = blk >> 3;
    const int wv   = rest & 3;
    const int qq   = rest >> 2;
    const int g    = qq & 15;
    const int a    = qq >> 4;
    const int y    = a * 8 + r8;
    if (y >= 98) return;

    const int lane = threadIdx.x & 63;
    const int col  = lane & 15;
    const int quad = lane >> 4;

    const int b_base = g * 16;
    const int i_base = y * 1024 + wv * 256;
    if (i_base >= I_TOTAL) return;

    const float s = 1.4426950408889634f;

    const float* up = ut + (size_t)bu[b_base + col] * DIM + quad * 8;
    float4 u0 = *(const float4*)(up);
    float4 u1 = *(const float4*)(up + 4);
    float4 u2 = *(const float4*)(up + 32);
    float4 u3 = *(const float4*)(up + 36);
    u0.x *= s; u0.y *= s; u0.z *= s; u0.w *= s;
    u1.x *= s; u1.y *= s; u1.z *= s; u1.w *= s;
    u2.x *= s; u2.y *= s; u2.z *= s; u2.w *= s;
    u3.x *= s; u3.y *= s; u3.z *= s; u3.w *= s;

    bf16x8 afr[5][2];
    float sw[5], swv[5];
#pragma unroll
    for (int c = 0; c < 5; ++c) {
        const float* wp = cw + c * DIM + quad * 8;
        float4 w0 = *(const float4*)(wp);
        float4 w1 = *(const float4*)(wp + 4);
        float4 w2 = *(const float4*)(wp + 32);
        float4 w3 = *(const float4*)(wp + 36);
        float4 m0 = make_float4(u0.x*w0.x, u0.y*w0.y, u0.z*w0.z, u0.w*w0.w);
        float4 m1 = make_float4(u1.x*w1.x, u1.y*w1.y, u1.z*w1.z, u1.w*w1.w);
        float4 m2 = make_float4(u2.x*w2.x, u2.y*w2.y, u2.z*w2.z, u2.w*w2.w);
        float4 m3 = make_float4(u3.x*w3.x, u3.y*w3.y, u3.z*w3.z, u3.w*w3.w);
        afr[c][0] = pack8(m0, m1);
        afr[c][1] = pack8(m2, m3);
        float w = __builtin_amdgcn_exp2f(clsb[c] * s);
        sw[c]  = rfl(w);
        swv[c] = rfl(w * vals[c]);
    }

#pragma unroll 1
    for (int t = 0; t < 16; ++t) {
        if (i_base + t * 16 >= I_TOTAL) break;
        int irow = i_base + t * 16 + col;
        int ic = irow < I_TOTAL ? irow : I_TOTAL - 1;
        const float* p2 = it + (size_t)ic * DIM + quad * 8;
        float4 q0 = *(const float4*)(p2);
        float4 q1 = *(const float4*)(p2 + 4);
        float4 q2 = *(const float4*)(p2 + 32);
        float4 q3 = *(const float4*)(p2 + 36);
        bf16x8 b0 = pack8(q0, q1);
        bf16x8 b1 = pack8(q2, q3);
        f32x4 acc[5];
        mfma_tile_sw(afr, b0, b1, acc);
        f32x4 r = softmax_vec(acc, sw, swv);
        int ie = i_base + t * 16 + quad * 4;
        if (ie + 4 <= I_TOTAL) {
            *(f32x4*)(out + (size_t)(b_base + col) * I_TOTAL + ie) = r;
        } else {
#pragma unroll
            for (int rr = 0; rr < 4; ++rr)
                if (ie + rr < I_TOTAL)
                    out[(size_t)(b_base + col) * I_TOTAL + ie + rr] = r[rr];
        }
    }
}

extern "C" void kernel_launch(void* const* d_in, const int* in_sizes, int n_in,
                              void* d_out, int out_size, void* d_ws, size_t ws_size,
                              hipStream_t stream) {
    const int*   bu   = (const int*)d_in[0];
    const float* ut   = (const float*)d_in[1];
    const float* it   = (const float*)d_in[2];
    const float* cw   = (const float*)d_in[3];
    const float* cb   = (const float*)d_in[4];
    const float* vals = (const float*)d_in[5];
    float* out = (float*)d_out;
    unsigned short* itbf = (unsigned short*)d_ws;    // 12.8 MB

    const size_t needed = (size_t)I_TOTAL * DIM * 2;

    if (ws_size >= needed) {
        conv_items<<<3125, 256, 0, stream>>>(it, itbf);
        gemm_softmax<<<6656, 64, 0, stream>>>(itbf, bu, ut, cw, cb, vals, out);
    } else {
        gemm_softmax_fb<<<6656, 64, 0, stream>>>(bu, ut, it, cw, cb, vals, out);
    }
}